// Round 3
// baseline (814.006 us; speedup 1.0000x reference)
//
#include <hip/hip_runtime.h>
#include <math.h>

namespace {

constexpr int KK = 4;
constexpr int DD = 16;
constexpr int BLOCK = 256;
constexpr int PTS = 2;                       // points per thread (keep VGPRs low!)
constexpr int ROWS_PER_BLOCK = BLOCK * PTS;  // 512
constexpr int TAB_LINV = 0;                  // KK*DD*DD = 1024 floats
constexpr int TAB_W    = KK * DD * DD;       // + KK*DD = 64 floats
constexpr int TAB_C0   = TAB_W + KK * DD;    // + KK floats
constexpr int TAB_SIZE = TAB_C0 + KK;        // 1092 floats
constexpr float LOG2PI = 1.8378770664093453f;

// ---------------------------------------------------------------------------
// Setup kernel: one block, 64 threads. Inverts the 4 upper-triangular 16x16
// factors, computes w_k = Linv_k * mu_k and c0_k, writes the table to d_ws.
// ---------------------------------------------------------------------------
__global__ __launch_bounds__(64)
void gmm_setup(const float* __restrict__ phi, const float* __restrict__ mu,
               const float* __restrict__ L, float* __restrict__ tab)
{
    __shared__ float sLinv[KK][DD][DD];
    const int tid = threadIdx.x;          // 0..63
    const int k = tid >> 4;
    const int j = tid & 15;

    // column j of Linv_k via back substitution (U x = e_j)
    {
        const float* Lk = L + k * DD * DD;
        float xv[DD];
        #pragma unroll
        for (int m = 0; m < DD; ++m) xv[m] = 0.0f;
        #pragma unroll
        for (int i = DD - 1; i >= 0; --i) {
            float s = (i == j) ? 1.0f : 0.0f;
            #pragma unroll
            for (int m = i + 1; m < DD; ++m)
                s -= Lk[i * DD + m] * xv[m];
            xv[i] = (i <= j) ? (s / Lk[i * DD + i]) : 0.0f;
        }
        #pragma unroll
        for (int i = 0; i < DD; ++i) {
            sLinv[k][i][j] = xv[i];
            tab[TAB_LINV + k * DD * DD + i * DD + j] = xv[i];
        }
    }
    __syncthreads();

    // w_k[i] = sum_j Linv_k[i][j] * mu_k[j]   (thread = (k,i))
    {
        const int i = j;
        float w = 0.0f;
        #pragma unroll
        for (int jj = 0; jj < DD; ++jj)
            w += sLinv[k][i][jj] * mu[k * DD + jj];
        tab[TAB_W + k * DD + i] = w;
    }

    if (tid < KK) {
        float logdet = 0.0f;
        #pragma unroll
        for (int i = 0; i < DD; ++i)
            logdet += logf(L[tid * DD * DD + i * DD + i]);
        tab[TAB_C0 + tid] = logf(phi[tid]) - 8.0f * LOG2PI - logdet;
    }
}

// ---------------------------------------------------------------------------
// Main kernel. __launch_bounds__(256,4) caps VGPRs at 128 (4 waves/EU =
// 16 waves/CU): round-2 post-mortem showed an uncapped build spilled
// (VGPR=256, 480 MB scratch traffic, 406 us). Single code path: loads use a
// clamped row index (no branch duplication), stores are predicated.
// ---------------------------------------------------------------------------
__global__ __launch_bounds__(BLOCK, 4)
void gmm_energy(const float* __restrict__ z, const float* __restrict__ tab,
                float* __restrict__ out, int N)
{
    __shared__ float sTab[TAB_SIZE];
    const int tid = threadIdx.x;

    for (int idx = tid; idx < TAB_SIZE; idx += BLOCK)
        sTab[idx] = tab[idx];
    __syncthreads();

    const int blockBase = blockIdx.x * ROWS_PER_BLOCK;

    // ---- load PTS rows (lane stride 64 B); clamp OOB rows to N-1 ----
    float zr[PTS][DD];
    #pragma unroll
    for (int p = 0; p < PTS; ++p) {
        int row = blockBase + p * BLOCK + tid;
        row = row < N ? row : N - 1;
        const float4* zp = reinterpret_cast<const float4*>(z + (size_t)row * DD);
        #pragma unroll
        for (int c = 0; c < 4; ++c) {
            float4 v = zp[c];
            zr[p][c * 4 + 0] = v.x;
            zr[p][c * 4 + 1] = v.y;
            zr[p][c * 4 + 2] = v.z;
            zr[p][c * 4 + 3] = v.w;
        }
    }

    // ---- per-component Mahalanobis via triangular matvec ----
    float lg[PTS][KK];
    #pragma unroll
    for (int k = 0; k < KK; ++k) {
        float q[PTS];
        #pragma unroll
        for (int p = 0; p < PTS; ++p) q[p] = 0.0f;
        #pragma unroll
        for (int i = 0; i < DD; ++i) {
            const float wk = sTab[TAB_W + k * DD + i];
            float acc[PTS];
            #pragma unroll
            for (int p = 0; p < PTS; ++p) acc[p] = -wk;
            #pragma unroll
            for (int j = i; j < DD; ++j) {
                const float cf = sTab[TAB_LINV + k * DD * DD + i * DD + j];
                #pragma unroll
                for (int p = 0; p < PTS; ++p)
                    acc[p] = fmaf(cf, zr[p][j], acc[p]);
            }
            #pragma unroll
            for (int p = 0; p < PTS; ++p)
                q[p] = fmaf(acc[p], acc[p], q[p]);
        }
        const float c0 = sTab[TAB_C0 + k];
        #pragma unroll
        for (int p = 0; p < PTS; ++p)
            lg[p][k] = fmaf(-0.5f, q[p], c0);
    }

    // ---- logsumexp over K=4, negate, store (coalesced dword stores) ----
    #pragma unroll
    for (int p = 0; p < PTS; ++p) {
        float m01 = fmaxf(lg[p][0], lg[p][1]);
        float m23 = fmaxf(lg[p][2], lg[p][3]);
        float m = fmaxf(m01, m23);
        float s = __expf(lg[p][0] - m) + __expf(lg[p][1] - m)
                + __expf(lg[p][2] - m) + __expf(lg[p][3] - m);
        float e = -(m + __logf(s));
        const int row = blockBase + p * BLOCK + tid;
        if (row < N) out[row] = e;
    }
}

} // namespace

extern "C" void kernel_launch(void* const* d_in, const int* in_sizes, int n_in,
                              void* d_out, int out_size, void* d_ws, size_t ws_size,
                              hipStream_t stream) {
    const float* z   = (const float*)d_in[0];   // [N,16]
    const float* phi = (const float*)d_in[1];   // [4]
    const float* mu  = (const float*)d_in[2];   // [4,16]
    const float* L   = (const float*)d_in[3];   // [4,16,16] upper-triangular
    float* out = (float*)d_out;                 // [N]
    float* tab = (float*)d_ws;                  // 1092-float table
    const int N = in_sizes[0] / DD;

    gmm_setup<<<1, 64, 0, stream>>>(phi, mu, L, tab);
    const int grid = (N + ROWS_PER_BLOCK - 1) / ROWS_PER_BLOCK;
    gmm_energy<<<grid, BLOCK, 0, stream>>>(z, tab, out, N);
}

// Round 4
// 129.370 us; speedup vs baseline: 6.2921x; 6.2921x over previous
//
#include <hip/hip_runtime.h>
#include <math.h>

namespace {

constexpr int KK = 4;
constexpr int DD = 16;
constexpr int BLOCK = 256;
constexpr int PTS = 4;                       // points per thread (R1-proven)
constexpr int CHUNKS = 2;                    // chunks of 1024 rows per block
constexpr int ROWS_PER_CHUNK = BLOCK * PTS;  // 1024
constexpr int ROWS_PER_BLOCK = ROWS_PER_CHUNK * CHUNKS;
constexpr float LOG2PI = 1.8378770664093453f;

// R1 structure verbatim (it ran <41 us; R2/R3 restructures both regressed to
// GB-scale spill-like traffic). Only change: CHUNKS outer loop amortizes the
// per-block prep over 2048 rows instead of 1024. No __launch_bounds__ min-wave
// hint (R3's build produced 2.2 GB of HBM traffic).
__global__ __launch_bounds__(BLOCK)
void gmm_energy(const float* __restrict__ z, const float* __restrict__ phi,
                const float* __restrict__ mu, const float* __restrict__ L,
                float* __restrict__ out, int N)
{
    __shared__ float sLinv[KK][DD][DD];   // inverse of upper-triangular L_k
    __shared__ float sW[KK][DD];          // w_k = Linv_k * mu_k
    __shared__ float sC0[KK];             // log(phi_k) - 8*log(2pi) - logdet

    const int tid = threadIdx.x;

    // ---- per-block prep: invert the 4 upper-triangular 16x16 factors ----
    if (tid < KK * DD) {
        const int k = tid >> 4;
        const int j = tid & 15;
        const float* Lk = L + k * DD * DD;
        float xv[DD];
        #pragma unroll
        for (int m = 0; m < DD; ++m) xv[m] = 0.0f;
        #pragma unroll
        for (int i = DD - 1; i >= 0; --i) {
            float s = (i == j) ? 1.0f : 0.0f;
            #pragma unroll
            for (int m = i + 1; m < DD; ++m)
                s -= Lk[i * DD + m] * xv[m];          // xv[m]==0 for m>j
            xv[i] = (i <= j) ? (s / Lk[i * DD + i]) : 0.0f;
        }
        #pragma unroll
        for (int i = 0; i < DD; ++i)
            sLinv[k][i][j] = xv[i];
    }
    __syncthreads();
    if (tid < KK * DD) {
        const int k = tid >> 4;
        const int i = tid & 15;
        float w = 0.0f;
        #pragma unroll
        for (int j = 0; j < DD; ++j)
            w += sLinv[k][i][j] * mu[k * DD + j];
        sW[k][i] = w;
    }
    if (tid < KK) {
        float logdet = 0.0f;
        #pragma unroll
        for (int i = 0; i < DD; ++i)
            logdet += __logf(L[tid * DD * DD + i * DD + i]);
        sC0[tid] = __logf(phi[tid]) - 8.0f * LOG2PI - logdet;
    }
    __syncthreads();

    #pragma unroll 1
    for (int chunk = 0; chunk < CHUNKS; ++chunk) {
        const int base = blockIdx.x * ROWS_PER_BLOCK + chunk * ROWS_PER_CHUNK
                       + tid * PTS;

        // ---- load 4 consecutive rows of z (four float4 loads each) ----
        float zr[PTS][DD];
        if (base + PTS <= N) {
            #pragma unroll
            for (int p = 0; p < PTS; ++p) {
                const float4* zp = reinterpret_cast<const float4*>(z + (size_t)(base + p) * DD);
                #pragma unroll
                for (int c = 0; c < 4; ++c) {
                    float4 v = zp[c];
                    zr[p][c * 4 + 0] = v.x;
                    zr[p][c * 4 + 1] = v.y;
                    zr[p][c * 4 + 2] = v.z;
                    zr[p][c * 4 + 3] = v.w;
                }
            }
        } else {
            #pragma unroll
            for (int p = 0; p < PTS; ++p) {
                if (base + p < N) {
                    const float4* zp = reinterpret_cast<const float4*>(z + (size_t)(base + p) * DD);
                    #pragma unroll
                    for (int c = 0; c < 4; ++c) {
                        float4 v = zp[c];
                        zr[p][c * 4 + 0] = v.x;
                        zr[p][c * 4 + 1] = v.y;
                        zr[p][c * 4 + 2] = v.z;
                        zr[p][c * 4 + 3] = v.w;
                    }
                } else {
                    #pragma unroll
                    for (int d = 0; d < DD; ++d) zr[p][d] = 0.0f;
                }
            }
        }

        // ---- per-component Mahalanobis via triangular matvec ----
        float lg[PTS][KK];
        #pragma unroll
        for (int k = 0; k < KK; ++k) {
            float q[PTS];
            #pragma unroll
            for (int p = 0; p < PTS; ++p) q[p] = 0.0f;
            #pragma unroll
            for (int i = 0; i < DD; ++i) {
                const float wk = sW[k][i];
                float acc[PTS];
                #pragma unroll
                for (int p = 0; p < PTS; ++p) acc[p] = -wk;
                #pragma unroll
                for (int j = i; j < DD; ++j) {
                    const float cf = sLinv[k][i][j];   // wave-uniform LDS broadcast
                    #pragma unroll
                    for (int p = 0; p < PTS; ++p)
                        acc[p] = fmaf(cf, zr[p][j], acc[p]);
                }
                #pragma unroll
                for (int p = 0; p < PTS; ++p)
                    q[p] = fmaf(acc[p], acc[p], q[p]);
            }
            const float c0 = sC0[k];
            #pragma unroll
            for (int p = 0; p < PTS; ++p)
                lg[p][k] = fmaf(-0.5f, q[p], c0);
        }

        // ---- logsumexp over K=4, negate, store ----
        float e[PTS];
        #pragma unroll
        for (int p = 0; p < PTS; ++p) {
            float m01 = fmaxf(lg[p][0], lg[p][1]);
            float m23 = fmaxf(lg[p][2], lg[p][3]);
            float m = fmaxf(m01, m23);
            float s = __expf(lg[p][0] - m) + __expf(lg[p][1] - m)
                    + __expf(lg[p][2] - m) + __expf(lg[p][3] - m);
            e[p] = -(m + __logf(s));
        }

        if (base + PTS <= N) {
            float4 res;
            res.x = e[0]; res.y = e[1]; res.z = e[2]; res.w = e[3];
            *reinterpret_cast<float4*>(out + base) = res;
        } else {
            #pragma unroll
            for (int p = 0; p < PTS; ++p) {
                if (base + p < N) out[base + p] = e[p];
            }
        }
    }
}

} // namespace

extern "C" void kernel_launch(void* const* d_in, const int* in_sizes, int n_in,
                              void* d_out, int out_size, void* d_ws, size_t ws_size,
                              hipStream_t stream) {
    const float* z   = (const float*)d_in[0];   // [N,16]
    const float* phi = (const float*)d_in[1];   // [4]
    const float* mu  = (const float*)d_in[2];   // [4,16]
    const float* L   = (const float*)d_in[3];   // [4,16,16] upper-triangular
    float* out = (float*)d_out;                 // [N]
    const int N = in_sizes[0] / DD;
    const int grid = (N + ROWS_PER_BLOCK - 1) / ROWS_PER_BLOCK;
    gmm_energy<<<grid, BLOCK, 0, stream>>>(z, phi, mu, L, out, N);
}

// Round 5
// 114.249 us; speedup vs baseline: 7.1249x; 1.1324x over previous
//
#include <hip/hip_runtime.h>
#include <math.h>

namespace {

constexpr int KK = 4;
constexpr int DD = 16;
constexpr int BLOCK = 256;
constexpr int PTS = 4;                       // points per thread (R1-proven)
constexpr int ROWS_PER_BLOCK = BLOCK * PTS;  // 1024
constexpr int TAB_LINV = 0;                  // KK*DD*DD = 1024 floats [k][i][j]
constexpr int TAB_W    = KK * DD * DD;       // + KK*DD = 64 floats
constexpr int TAB_C0   = TAB_W + KK * DD;    // + KK floats
constexpr float LOG2PI = 1.8378770664093453f;

// ---------------------------------------------------------------------------
// Setup: one block, 64 threads. Inverts the 4 upper-triangular 16x16 factors,
// computes w_k = Linv_k*mu_k and c0_k, writes the 1092-float table to d_ws.
// Register-heavy unrolled back-substitution is fine here: single block.
// ---------------------------------------------------------------------------
__global__ __launch_bounds__(64)
void gmm_setup(const float* __restrict__ phi, const float* __restrict__ mu,
               const float* __restrict__ L, float* __restrict__ tab)
{
    __shared__ float sLinv[KK][DD][DD];
    const int tid = threadIdx.x;          // 0..63
    const int k = tid >> 4;
    const int j = tid & 15;

    {   // column j of Linv_k via back substitution (U x = e_j)
        const float* Lk = L + k * DD * DD;
        float xv[DD];
        #pragma unroll
        for (int m = 0; m < DD; ++m) xv[m] = 0.0f;
        #pragma unroll
        for (int i = DD - 1; i >= 0; --i) {
            float s = (i == j) ? 1.0f : 0.0f;
            #pragma unroll
            for (int m = i + 1; m < DD; ++m)
                s -= Lk[i * DD + m] * xv[m];
            xv[i] = (i <= j) ? (s / Lk[i * DD + i]) : 0.0f;
        }
        #pragma unroll
        for (int i = 0; i < DD; ++i) {
            sLinv[k][i][j] = xv[i];
            tab[TAB_LINV + k * DD * DD + i * DD + j] = xv[i];
        }
    }
    __syncthreads();

    {   // w_k[i] = sum_j Linv_k[i][j] * mu_k[j]   (thread = (k,i))
        const int i = j;
        float w = 0.0f;
        #pragma unroll
        for (int jj = 0; jj < DD; ++jj)
            w += sLinv[k][i][jj] * mu[k * DD + jj];
        tab[TAB_W + k * DD + i] = w;
    }

    if (tid < KK) {
        float logdet = 0.0f;
        #pragma unroll
        for (int i = 0; i < DD; ++i)
            logdet += logf(L[tid * DD * DD + i * DD + i]);
        tab[TAB_C0 + tid] = logf(phi[tid]) - 8.0f * LOG2PI - logdet;
    }
}

// ---------------------------------------------------------------------------
// Main kernel: R1's proven body, but coefficients come from the global table
// with unroll-constant (wave-uniform) indices -> compiler emits s_load into
// SGPRs (constant cache). No LDS, no per-block prep, no barriers.
// NO __launch_bounds__ min-wave hint (R2/R3 post-mortem: it made the
// allocator spill GBs of scratch).
// ---------------------------------------------------------------------------
__global__ __launch_bounds__(BLOCK)
void gmm_energy(const float* __restrict__ z, const float* __restrict__ tab,
                float* __restrict__ out, int N)
{
    const int tid = threadIdx.x;
    const int base = blockIdx.x * ROWS_PER_BLOCK + tid * PTS;

    // ---- load 4 consecutive rows of z (four float4 loads each) ----
    float zr[PTS][DD];
    if (base + PTS <= N) {
        #pragma unroll
        for (int p = 0; p < PTS; ++p) {
            const float4* zp = reinterpret_cast<const float4*>(z + (size_t)(base + p) * DD);
            #pragma unroll
            for (int c = 0; c < 4; ++c) {
                float4 v = zp[c];
                zr[p][c * 4 + 0] = v.x;
                zr[p][c * 4 + 1] = v.y;
                zr[p][c * 4 + 2] = v.z;
                zr[p][c * 4 + 3] = v.w;
            }
        }
    } else {
        #pragma unroll
        for (int p = 0; p < PTS; ++p) {
            if (base + p < N) {
                const float4* zp = reinterpret_cast<const float4*>(z + (size_t)(base + p) * DD);
                #pragma unroll
                for (int c = 0; c < 4; ++c) {
                    float4 v = zp[c];
                    zr[p][c * 4 + 0] = v.x;
                    zr[p][c * 4 + 1] = v.y;
                    zr[p][c * 4 + 2] = v.z;
                    zr[p][c * 4 + 3] = v.w;
                }
            } else {
                #pragma unroll
                for (int d = 0; d < DD; ++d) zr[p][d] = 0.0f;
            }
        }
    }

    // ---- per-component Mahalanobis via triangular matvec ----
    float lg[PTS][KK];
    #pragma unroll
    for (int k = 0; k < KK; ++k) {
        float q[PTS];
        #pragma unroll
        for (int p = 0; p < PTS; ++p) q[p] = 0.0f;
        #pragma unroll
        for (int i = 0; i < DD; ++i) {
            const float wk = tab[TAB_W + k * DD + i];          // uniform -> SGPR
            float acc[PTS];
            #pragma unroll
            for (int p = 0; p < PTS; ++p) acc[p] = -wk;
            #pragma unroll
            for (int j = i; j < DD; ++j) {
                const float cf = tab[TAB_LINV + k * DD * DD + i * DD + j]; // uniform -> SGPR
                #pragma unroll
                for (int p = 0; p < PTS; ++p)
                    acc[p] = fmaf(cf, zr[p][j], acc[p]);
            }
            #pragma unroll
            for (int p = 0; p < PTS; ++p)
                q[p] = fmaf(acc[p], acc[p], q[p]);
        }
        const float c0 = tab[TAB_C0 + k];                      // uniform -> SGPR
        #pragma unroll
        for (int p = 0; p < PTS; ++p)
            lg[p][k] = fmaf(-0.5f, q[p], c0);
    }

    // ---- logsumexp over K=4, negate, store ----
    float e[PTS];
    #pragma unroll
    for (int p = 0; p < PTS; ++p) {
        float m01 = fmaxf(lg[p][0], lg[p][1]);
        float m23 = fmaxf(lg[p][2], lg[p][3]);
        float m = fmaxf(m01, m23);
        float s = __expf(lg[p][0] - m) + __expf(lg[p][1] - m)
                + __expf(lg[p][2] - m) + __expf(lg[p][3] - m);
        e[p] = -(m + __logf(s));
    }

    if (base + PTS <= N) {
        float4 res;
        res.x = e[0]; res.y = e[1]; res.z = e[2]; res.w = e[3];
        *reinterpret_cast<float4*>(out + base) = res;
    } else {
        #pragma unroll
        for (int p = 0; p < PTS; ++p) {
            if (base + p < N) out[base + p] = e[p];
        }
    }
}

} // namespace

extern "C" void kernel_launch(void* const* d_in, const int* in_sizes, int n_in,
                              void* d_out, int out_size, void* d_ws, size_t ws_size,
                              hipStream_t stream) {
    const float* z   = (const float*)d_in[0];   // [N,16]
    const float* phi = (const float*)d_in[1];   // [4]
    const float* mu  = (const float*)d_in[2];   // [4,16]
    const float* L   = (const float*)d_in[3];   // [4,16,16] upper-triangular
    float* out = (float*)d_out;                 // [N]
    float* tab = (float*)d_ws;                  // 1092-float table in scratch

    const int N = in_sizes[0] / DD;
    gmm_setup<<<1, 64, 0, stream>>>(phi, mu, L, tab);
    const int grid = (N + ROWS_PER_BLOCK - 1) / ROWS_PER_BLOCK;
    gmm_energy<<<grid, BLOCK, 0, stream>>>(z, tab, out, N);
}

// Round 6
// 113.841 us; speedup vs baseline: 7.1504x; 1.0036x over previous
//
#include <hip/hip_runtime.h>
#include <math.h>

namespace {

constexpr int KK = 4;
constexpr int DD = 16;
constexpr int BLOCK = 256;
constexpr int PTS = 2;                       // 2 points/thread: zr=32 VGPRs, target 4-5 waves/SIMD
constexpr int ROWS_PER_BLOCK = BLOCK * PTS;  // 512
constexpr int TAB_LINV = 0;                  // KK*DD*DD = 1024 floats [k][i][j]
constexpr int TAB_W    = KK * DD * DD;       // + KK*DD = 64 floats
constexpr int TAB_C0   = TAB_W + KK * DD;    // + KK floats
constexpr float LOG2PI = 1.8378770664093453f;

// ---------------------------------------------------------------------------
// Setup: one block, 64 threads. Inverts the 4 upper-triangular 16x16 factors,
// computes w_k = Linv_k*mu_k and c0_k, writes the 1092-float table to d_ws.
// ---------------------------------------------------------------------------
__global__ __launch_bounds__(64)
void gmm_setup(const float* __restrict__ phi, const float* __restrict__ mu,
               const float* __restrict__ L, float* __restrict__ tab)
{
    __shared__ float sLinv[KK][DD][DD];
    const int tid = threadIdx.x;          // 0..63
    const int k = tid >> 4;
    const int j = tid & 15;

    {   // column j of Linv_k via back substitution (U x = e_j)
        const float* Lk = L + k * DD * DD;
        float xv[DD];
        #pragma unroll
        for (int m = 0; m < DD; ++m) xv[m] = 0.0f;
        #pragma unroll
        for (int i = DD - 1; i >= 0; --i) {
            float s = (i == j) ? 1.0f : 0.0f;
            #pragma unroll
            for (int m = i + 1; m < DD; ++m)
                s -= Lk[i * DD + m] * xv[m];
            xv[i] = (i <= j) ? (s / Lk[i * DD + i]) : 0.0f;
        }
        #pragma unroll
        for (int i = 0; i < DD; ++i) {
            sLinv[k][i][j] = xv[i];
            tab[TAB_LINV + k * DD * DD + i * DD + j] = xv[i];
        }
    }
    __syncthreads();

    {   // w_k[i] = sum_j Linv_k[i][j] * mu_k[j]   (thread = (k,i))
        const int i = j;
        float w = 0.0f;
        #pragma unroll
        for (int jj = 0; jj < DD; ++jj)
            w += sLinv[k][i][jj] * mu[k * DD + jj];
        tab[TAB_W + k * DD + i] = w;
    }

    if (tid < KK) {
        float logdet = 0.0f;
        #pragma unroll
        for (int i = 0; i < DD; ++i)
            logdet += logf(L[tid * DD * DD + i * DD + i]);
        tab[TAB_C0 + tid] = logf(phi[tid]) - 8.0f * LOG2PI - logdet;
    }
}

// ---------------------------------------------------------------------------
// Main kernel: coefficients from global table with unroll-constant uniform
// indices -> s_load / constant cache (scalar pipe, zero VGPR cost). No LDS,
// no per-block prep, no barriers. PTS=2 keeps the live set ~60-80 VGPRs.
// NO __launch_bounds__ min-wave hint (R2/R3: it caused GB-scale spills).
// ---------------------------------------------------------------------------
__global__ __launch_bounds__(BLOCK)
void gmm_energy(const float* __restrict__ z, const float* __restrict__ tab,
                float* __restrict__ out, int N)
{
    const int tid = threadIdx.x;
    const int base = blockIdx.x * ROWS_PER_BLOCK + tid * PTS;

    // ---- load 2 consecutive rows of z (four float4 loads each) ----
    float zr[PTS][DD];
    if (base + PTS <= N) {
        #pragma unroll
        for (int p = 0; p < PTS; ++p) {
            const float4* zp = reinterpret_cast<const float4*>(z + (size_t)(base + p) * DD);
            #pragma unroll
            for (int c = 0; c < 4; ++c) {
                float4 v = zp[c];
                zr[p][c * 4 + 0] = v.x;
                zr[p][c * 4 + 1] = v.y;
                zr[p][c * 4 + 2] = v.z;
                zr[p][c * 4 + 3] = v.w;
            }
        }
    } else {
        #pragma unroll
        for (int p = 0; p < PTS; ++p) {
            if (base + p < N) {
                const float4* zp = reinterpret_cast<const float4*>(z + (size_t)(base + p) * DD);
                #pragma unroll
                for (int c = 0; c < 4; ++c) {
                    float4 v = zp[c];
                    zr[p][c * 4 + 0] = v.x;
                    zr[p][c * 4 + 1] = v.y;
                    zr[p][c * 4 + 2] = v.z;
                    zr[p][c * 4 + 3] = v.w;
                }
            } else {
                #pragma unroll
                for (int d = 0; d < DD; ++d) zr[p][d] = 0.0f;
            }
        }
    }

    // ---- per-component Mahalanobis via triangular matvec ----
    float lg[PTS][KK];
    #pragma unroll
    for (int k = 0; k < KK; ++k) {
        float q[PTS];
        #pragma unroll
        for (int p = 0; p < PTS; ++p) q[p] = 0.0f;
        #pragma unroll
        for (int i = 0; i < DD; ++i) {
            const float wk = tab[TAB_W + k * DD + i];          // uniform -> SGPR
            float acc[PTS];
            #pragma unroll
            for (int p = 0; p < PTS; ++p) acc[p] = -wk;
            #pragma unroll
            for (int j = i; j < DD; ++j) {
                const float cf = tab[TAB_LINV + k * DD * DD + i * DD + j]; // uniform -> SGPR
                #pragma unroll
                for (int p = 0; p < PTS; ++p)
                    acc[p] = fmaf(cf, zr[p][j], acc[p]);
            }
            #pragma unroll
            for (int p = 0; p < PTS; ++p)
                q[p] = fmaf(acc[p], acc[p], q[p]);
        }
        const float c0 = tab[TAB_C0 + k];                      // uniform -> SGPR
        #pragma unroll
        for (int p = 0; p < PTS; ++p)
            lg[p][k] = fmaf(-0.5f, q[p], c0);
    }

    // ---- logsumexp over K=4, negate, store ----
    float e[PTS];
    #pragma unroll
    for (int p = 0; p < PTS; ++p) {
        float m01 = fmaxf(lg[p][0], lg[p][1]);
        float m23 = fmaxf(lg[p][2], lg[p][3]);
        float m = fmaxf(m01, m23);
        float s = __expf(lg[p][0] - m) + __expf(lg[p][1] - m)
                + __expf(lg[p][2] - m) + __expf(lg[p][3] - m);
        e[p] = -(m + __logf(s));
    }

    if (base + PTS <= N) {
        float2 res;
        res.x = e[0]; res.y = e[1];
        *reinterpret_cast<float2*>(out + base) = res;
    } else {
        #pragma unroll
        for (int p = 0; p < PTS; ++p) {
            if (base + p < N) out[base + p] = e[p];
        }
    }
}

} // namespace

extern "C" void kernel_launch(void* const* d_in, const int* in_sizes, int n_in,
                              void* d_out, int out_size, void* d_ws, size_t ws_size,
                              hipStream_t stream) {
    const float* z   = (const float*)d_in[0];   // [N,16]
    const float* phi = (const float*)d_in[1];   // [4]
    const float* mu  = (const float*)d_in[2];   // [4,16]
    const float* L   = (const float*)d_in[3];   // [4,16,16] upper-triangular
    float* out = (float*)d_out;                 // [N]
    float* tab = (float*)d_ws;                  // 1092-float table in scratch

    const int N = in_sizes[0] / DD;
    gmm_setup<<<1, 64, 0, stream>>>(phi, mu, L, tab);
    const int grid = (N + ROWS_PER_BLOCK - 1) / ROWS_PER_BLOCK;
    gmm_energy<<<grid, BLOCK, 0, stream>>>(z, tab, out, N);
}